// Round 1
// baseline (153.291 us; speedup 1.0000x reference)
//
#include <hip/hip_runtime.h>

// YOLO-style loss: y_pred (1024,28,28,30) f32, y_true (1024,28,28,5) f32 -> scalar f32.
// DRAM floor: 112.4 MB read @ ~6.3 TB/s ≈ 18 us. Harness poison fills (2 x 385 MB ≈ 112 us)
// dominate dur_us and are not controllable from kernel_launch.
// R1 strided loads ~55us; R2 LDS+atomics 65us; R3 partials ~45us; R4 global_load_lds ~40us;
// R5 barrier-free wave-private staging (~40us kernel, dur 152).
// R6 (this): persistent waves + double-buffered wave-private LDS slabs fed by
// global_load_lds DMA (7x16B + 2x4B pred, 5x4B y_true per tile) + counted
// s_waitcnt vmcnt(14) so the next tile's 14 DMA ops stay in flight across the
// current tile's LDS-read/compute (T3/T4 idiom: never drain vmcnt to 0 mid-loop).
// Zero barriers (slabs are wave-private; same-wave vmcnt ordering suffices).
// Grid = 1024 blocks x 128 thr = 2048 waves, 4 blocks/CU resident exactly
// (LDS 35840 B/block -> floor(163840/35840)=4), ~6 tiles/wave.

#define S_GRID 28
#define N_CELLS (1024 * S_GRID * S_GRID)     // 802816
#define CPW 64                               // cells per wave-tile
#define N_TILES (N_CELLS / CPW)              // 12544
#define WPB 2                                // waves per block
#define BLOCK (WPB * 64)                     // 128
#define NBLOCKS 1024                         // 4 resident blocks/CU * 256 CU
#define NWAVES (NBLOCKS * WPB)               // 2048 persistent waves

typedef unsigned int u32;

__device__ __forceinline__ void async16(const float* g, float* l) {
    __builtin_amdgcn_global_load_lds((const __attribute__((address_space(1))) u32*)g,
                                     (__attribute__((address_space(3))) u32*)l, 16, 0, 0);
}
__device__ __forceinline__ void async4(const float* g, float* l) {
    __builtin_amdgcn_global_load_lds((const __attribute__((address_space(1))) u32*)g,
                                     (__attribute__((address_space(3))) u32*)l, 4, 0, 0);
}

// Issue the 14 DMA ops staging one tile (1920 pred floats + 320 true floats).
// LDS dst is wave-uniform base (+ lane*size applied by HW); global src is per-lane.
__device__ __forceinline__ void stage(const float* __restrict__ yp,
                                      const float* __restrict__ yt,
                                      int tile, int lane,
                                      float* spred, float* syt) {
    const float* gp = yp + (size_t)tile * (CPW * 30);
#pragma unroll
    for (int j = 0; j < 7; ++j)                      // 7 * 1024 B = 7168 B
        async16(gp + j * 256 + lane * 4, spred + j * 256);
    async4(gp + 1792 + lane, spred + 1792);          // + 2 * 256 B = 7680 B total
    async4(gp + 1856 + lane, spred + 1856);
    const float* gt = yt + (size_t)tile * (CPW * 5);
#pragma unroll
    for (int j = 0; j < 5; ++j)                      // 5 * 256 B = 1280 B
        async4(gt + j * 64 + lane, syt + j * 64);
}

__device__ __forceinline__ float iou_calc(float bx, float by, float bw, float bh,
                                          float tx, float ty, float tw, float th,
                                          float gi, float gj) {
    float acx = (gj + bx) * 8.0f;
    float acy = (gi + by) * 8.0f;
    float aw  = bw * 224.0f;
    float ah  = bh * 224.0f;
    float ax1 = acx - aw * 0.5f, ax2 = acx + aw * 0.5f;
    float ay1 = acy - ah * 0.5f, ay2 = acy + ah * 0.5f;
    float bcx = (gj + tx) * 8.0f;
    float bcy = (gi + ty) * 8.0f;
    float btw = tw * 224.0f;
    float bth = th * 224.0f;
    float bx1 = bcx - btw * 0.5f, bx2 = bcx + btw * 0.5f;
    float by1 = bcy - bth * 0.5f, by2 = bcy + bth * 0.5f;

    float iw = fmaxf(fminf(ax2, bx2) - fmaxf(ax1, bx1), 0.0f);
    float ih = fmaxf(fminf(ay2, by2) - fmaxf(ay1, by1), 0.0f);
    float inter = iw * ih;
    float area_a = fmaxf(ax2 - ax1, 0.0f) * fmaxf(ay2 - ay1, 0.0f);
    float area_b = fmaxf(bx2 - bx1, 0.0f) * fmaxf(by2 - by1, 0.0f);
    return inter / (area_a + area_b - inter + 1e-12f);
}

__global__ __launch_bounds__(BLOCK, 2) void yolo_loss_kernel(const float* __restrict__ yp,
                                                             const float* __restrict__ yt,
                                                             float* __restrict__ partials) {
    // wave-private double-buffered slabs, raw global layout (DMA writes linearly)
    __shared__ __align__(16) float sp[WPB][2][CPW * 30];   // 2*2*7680 B = 30720 B
    __shared__ __align__(16) float sy[WPB][2][CPW * 5];    // 2*2*1280 B =  5120 B

    int tid  = threadIdx.x;
    int lane = tid & 63;
    int wave = tid >> 6;
    int gwave = blockIdx.x * WPB + wave;

    float acc = 0.0f;
    int buf = 0;

    // prologue: prefetch first tile (every wave has >=1: NWAVES <= N_TILES)
    stage(yp, yt, gwave, lane, sp[wave][0], sy[wave][0]);

    for (int t = gwave; t < N_TILES; t += NWAVES) {
        int tn = t + NWAVES;
        if (tn < N_TILES) {
            // issue next tile's 14 DMA ops into the other buffer, THEN wait so
            // that only those 14 remain outstanding -> tile t is complete in LDS
            stage(yp, yt, tn, lane, sp[wave][buf ^ 1], sy[wave][buf ^ 1]);
            asm volatile("s_waitcnt vmcnt(14)" ::: "memory");
        } else {
            asm volatile("s_waitcnt vmcnt(0)" ::: "memory");
        }

        const float* spw = sp[wave][buf];
        const float* syw = sy[wave][buf];

        // own cell's 30 channels: 15 x ds_read_b64, stride 120 B (4-way, ~free)
        const float2* p2 = (const float2*)(spw + lane * 30);
        float pr[30];
#pragma unroll
        for (int k = 0; k < 15; ++k) {
            float2 q = p2[k];
            pr[2 * k]     = q.x;
            pr[2 * k + 1] = q.y;
        }
        // own cell's 5 true floats: stride-5 dwords -> 2-way (free)
        float tc = syw[lane * 5 + 0];
        float tx = syw[lane * 5 + 1];
        float ty = syw[lane * 5 + 2];
        float tw = syw[lane * 5 + 3];
        float th = syw[lane * 5 + 4];

        int cell = t * CPW + lane;
        int ij = cell % (S_GRID * S_GRID);
        float gi = (float)(ij / S_GRID);
        float gj = (float)(ij % S_GRID);

        float iou0 = iou_calc(pr[0], pr[1], pr[2], pr[3], tx, ty, tw, th, gi, gj);
        float iou1 = iou_calc(pr[5], pr[6], pr[7], pr[8], tx, ty, tw, th, gi, gj);
        bool choose1 = !(iou0 > iou1);

        float conf_pred = choose1 ? pr[9] : pr[4];
        float conf_true = choose1 ? iou1 : iou0;
        float xp  = choose1 ? pr[5] : pr[0];
        float ypv = choose1 ? pr[6] : pr[1];

        float dcf = conf_pred - conf_true;
        float d0 = xp - tx, d1 = ypv - ty;

        int cls = (int)tc - 1;   // -1 => one-hot all zeros
        float lcls = 0.0f;
#pragma unroll
        for (int k = 0; k < 20; ++k) {
            float oh = (k == cls) ? 1.0f : 0.0f;
            float d = pr[10 + k] - oh;
            lcls += d * d;
        }

        float obj_loss   = dcf * dcf + 5.0f * (d0 * d0 + d1 * d1) + lcls;
        float noobj_loss = 0.5f * (pr[4] * pr[4] + pr[9] * pr[9]);
        acc += (tc != 0.0f) ? obj_loss : noobj_loss;

        buf ^= 1;
    }

    // one wave-local reduction at the end; one partial per wave, NO barrier
#pragma unroll
    for (int off = 32; off > 0; off >>= 1) {
        acc += __shfl_down(acc, off, 64);
    }
    if (lane == 0) partials[gwave] = acc;
}

__global__ __launch_bounds__(256) void reduce_kernel(const float* __restrict__ partials,
                                                     float* __restrict__ out) {
    int tid = threadIdx.x;
    float s = 0.0f;
#pragma unroll
    for (int k = 0; k < 8; ++k) {            // 8 * 256 = 2048 exact
        s += partials[k * 256 + tid];
    }
#pragma unroll
    for (int off = 32; off > 0; off >>= 1) {
        s += __shfl_down(s, off, 64);
    }
    __shared__ float wsum[4];
    int lane = tid & 63;
    int wid  = tid >> 6;
    if (lane == 0) wsum[wid] = s;
    __syncthreads();
    if (tid == 0) {
        out[0] = (wsum[0] + wsum[1] + wsum[2] + wsum[3]) * (1.0f / 1024.0f);
    }
}

extern "C" void kernel_launch(void* const* d_in, const int* in_sizes, int n_in,
                              void* d_out, int out_size, void* d_ws, size_t ws_size,
                              hipStream_t stream) {
    const float* y_pred = (const float*)d_in[0];
    const float* y_true = (const float*)d_in[1];
    float* out = (float*)d_out;
    float* partials = (float*)d_ws;   // 2048 floats, fully overwritten each call

    yolo_loss_kernel<<<NBLOCKS, BLOCK, 0, stream>>>(y_pred, y_true, partials);
    reduce_kernel<<<1, 256, 0, stream>>>(partials, out);
}